// Round 6
// baseline (1354.886 us; speedup 1.0000x reference)
//
#include <hip/hip_runtime.h>
#include <hip/hip_bf16.h>

typedef unsigned int  uint_t;
typedef unsigned short ushort_t;

#define NN 50000
#define NE 800000
#define NBLK 196   // cdiv(NN,256) for CSR kernels
#define NDBLK 391  // cdiv(NN,128) for dense

static inline int cdiv(long long a, long long b) { return (int)((a + b - 1) / b); }

// ---- bf16 pair helpers (element j at low 16 bits) ----
__device__ inline float bflo(uint_t u) { return __uint_as_float(u << 16); }
__device__ inline float bfhi(uint_t u) { return __uint_as_float(u & 0xffff0000u); }
__device__ inline uint_t packbf(float x, float y) {  // RNE
    uint_t xu = __float_as_uint(x), yu = __float_as_uint(y);
    xu += 0x7fffu + ((xu >> 16) & 1u);
    yu += 0x7fffu + ((yu >> 16) & 1u);
    return (xu >> 16) | (yu & 0xffff0000u);
}
__device__ inline float bf1(ushort_t u) { return __uint_as_float(((uint_t)u) << 16); }
__device__ inline ushort_t packbf1(float x) {
    uint_t xu = __float_as_uint(x);
    xu += 0x7fffu + ((xu >> 16) & 1u);
    return (ushort_t)(xu >> 16);
}

// ---------------- CSR build ----------------

__global__ void k_prep(int* __restrict__ deg, float* __restrict__ bnacc) {
    int i = blockIdx.x * blockDim.x + threadIdx.x;
    if (i < NN) deg[i] = 0;
    if (i < 768) bnacc[i] = 0.0f;
}

__global__ void k_hist(const int* __restrict__ dst, int* __restrict__ deg) {
    int e = blockIdx.x * blockDim.x + threadIdx.x;
    if (e < NE) {
        int d = dst[e];
        if ((unsigned)d < NN) atomicAdd(&deg[d], 1);
    }
}

__global__ void k_bsum(const int* __restrict__ deg, int* __restrict__ bsum) {
    __shared__ int l[256];
    int tid = threadIdx.x;
    int i = blockIdx.x * 256 + tid;
    l[tid] = (i < NN) ? deg[i] : 0;
    __syncthreads();
    for (int o = 128; o > 0; o >>= 1) {
        if (tid < o) l[tid] += l[tid + o];
        __syncthreads();
    }
    if (tid == 0) bsum[blockIdx.x] = l[0];
}

__global__ void k_bscan(const int* __restrict__ bsum, int* __restrict__ boff,
                        int* __restrict__ row_ptr) {
    __shared__ int l[256];
    int tid = threadIdx.x;
    int v = (tid < NBLK) ? bsum[tid] : 0;
    l[tid] = v;
    __syncthreads();
    for (int o = 1; o < 256; o <<= 1) {
        int t = (tid >= o) ? l[tid - o] : 0;
        __syncthreads();
        l[tid] += t;
        __syncthreads();
    }
    boff[tid] = l[tid] - v;            // exclusive block offset
    if (tid == 255) row_ptr[NN] = l[255];  // total
}

__global__ void k_rowptr(const int* __restrict__ deg, const int* __restrict__ boff,
                         int* __restrict__ row_ptr, int* __restrict__ cursor,
                         float* __restrict__ dis) {
    __shared__ int l[256];
    int tid = threadIdx.x;
    int i = blockIdx.x * 256 + tid;
    int v = (i < NN) ? deg[i] : 0;
    l[tid] = v;
    __syncthreads();
    for (int o = 1; o < 256; o <<= 1) {
        int t = (tid >= o) ? l[tid - o] : 0;
        __syncthreads();
        l[tid] += t;
        __syncthreads();
    }
    if (i < NN) {
        int excl = boff[blockIdx.x] + l[tid] - v;
        row_ptr[i] = excl;
        cursor[i] = excl;
        dis[i] = rsqrtf((float)(v + 1));  // +1 self-loop
    }
}

__global__ void k_fill(const int* __restrict__ src, const int* __restrict__ dst,
                       const float* __restrict__ dis,
                       int* __restrict__ cursor, int* __restrict__ col,
                       float* __restrict__ wgt) {
    int e = blockIdx.x * blockDim.x + threadIdx.x;
    if (e < NE) {
        int s = src[e], d = dst[e];
        if ((unsigned)s < NN && (unsigned)d < NN) {
            int p = atomicAdd(&cursor[d], 1);
            col[p] = s;
            wgt[p] = dis[s] * dis[d];
        }
    }
}

// ---------------- dense: H = in_tf(X) @ W (+ b) ----------------
// One thread per node; x row in registers; BN-scaled W staged in LDS;
// BN shift folded into per-output bias. blockIdx.y selects output half.
template<int FI, int FO, int IN_BN, int OUT_BIAS, int IN_F32, int OUT_F32>
__global__ __launch_bounds__(128, 2)
void k_dense(const void* __restrict__ Xv, const float* __restrict__ W,
             const float* __restrict__ bnacc, const float* __restrict__ g,
             const float* __restrict__ be, const float* __restrict__ b,
             void* __restrict__ Hv) {
    constexpr int FOH  = FO / 2;             // outputs per block (FO even)
    constexpr int FOHP = (FOH + 3) & ~3;     // padded to multiple of 4
    constexpr int KP   = FI / 2;             // bf16 pairs (FI even)

    __shared__ __align__(16) float wlds[FI * FOHP];
    __shared__ float biasl[FOHP];
    __shared__ float scl[FI], shl[FI];

    int tid  = threadIdx.x;
    int yoff = blockIdx.y * FOH;

    if (IN_BN) {
        if (tid < FI) {
            const float inv_n = 1.0f / NN;
            float mu = bnacc[tid] * inv_n;
            float va = bnacc[96 + tid] * inv_n - mu * mu;
            float r  = rsqrtf(va + 1e-5f);
            float sc = g[tid] * r;
            scl[tid] = sc;
            shl[tid] = be[tid] - mu * sc;
        }
        __syncthreads();
    }
    // stage W (BN-scaled) into LDS, zero-padded columns
    for (int t = tid; t < FI * FOHP; t += 128) {
        int k = t / FOHP, jp = t - k * FOHP;
        float w = (jp < FOH) ? W[k * FO + yoff + jp] : 0.0f;
        if (IN_BN) w *= scl[k];
        wlds[t] = w;
    }
    // folded bias: b[j] + sum_k shl[k]*W[k][j]
    if (tid < FOHP) {
        float acc = 0.0f;
        if (tid < FOH) {
            if (OUT_BIAS) acc = b[yoff + tid];
            if (IN_BN) {
                #pragma unroll 8
                for (int k = 0; k < FI; ++k) acc = fmaf(shl[k], W[k * FO + yoff + tid], acc);
            }
        }
        biasl[tid] = acc;
    }
    __syncthreads();

    int node = blockIdx.x * 128 + tid;
    if (node >= NN) return;

    // load x row into registers (fully static indexing)
    float  xf[IN_F32 ? FI : 1];
    uint_t xp[IN_F32 ? 1 : KP];
    if (IN_F32) {
        const float4* xr = (const float4*)((const float*)Xv + (size_t)node * FI);
        #pragma unroll
        for (int q = 0; q < FI / 4; ++q) ((float4*)xf)[q] = xr[q];
    } else {
        const uint_t* xr = (const uint_t*)Xv + (size_t)node * KP;
        #pragma unroll
        for (int kp = 0; kp < KP; ++kp) xp[kp] = xr[kp];
    }

    for (int j0 = 0; j0 < FOHP; j0 += 4) {
        float a[4];
        #pragma unroll
        for (int q = 0; q < 4; ++q) a[q] = biasl[j0 + q];
        #pragma unroll
        for (int kp = 0; kp < KP; ++kp) {
            float xl, xh;
            if (IN_F32) { xl = xf[2 * kp]; xh = xf[2 * kp + 1]; }
            else        { xl = bflo(xp[kp]); xh = bfhi(xp[kp]); }
            if (IN_BN)  { xl = fmaxf(xl, 0.0f); xh = fmaxf(xh, 0.0f); }
            const float4 w0 = *(const float4*)&wlds[(2 * kp) * FOHP + j0];
            const float4 w1 = *(const float4*)&wlds[(2 * kp + 1) * FOHP + j0];
            a[0] = fmaf(xl, w0.x, a[0]); a[1] = fmaf(xl, w0.y, a[1]);
            a[2] = fmaf(xl, w0.z, a[2]); a[3] = fmaf(xl, w0.w, a[3]);
            a[0] = fmaf(xh, w1.x, a[0]); a[1] = fmaf(xh, w1.y, a[1]);
            a[2] = fmaf(xh, w1.z, a[2]); a[3] = fmaf(xh, w1.w, a[3]);
        }
        size_t o = (size_t)node * FO + yoff;
        #pragma unroll
        for (int q = 0; q < 4; ++q) {
            int jp = j0 + q;
            if (jp < FOH) {
                if (OUT_F32) ((float*)Hv)[o + jp] = a[q];
                else         ((ushort_t*)Hv)[o + jp] = packbf1(a[q]);
            }
        }
    }
}

// ---------------- CSR gather (bf16 in/out, unroll-8) ----------------
template<int FO, int IN_BN, int OUT_BIAS>
__global__ void k_gather(const ushort_t* __restrict__ h, const int* __restrict__ row_ptr,
                         const int* __restrict__ col, const float* __restrict__ wgt,
                         const float* __restrict__ dis,
                         const float* __restrict__ bnacc, const float* __restrict__ g,
                         const float* __restrict__ be,
                         const float* __restrict__ b, ushort_t* __restrict__ A) {
    constexpr int F2 = FO / 2;
    int t = blockIdx.x * blockDim.x + threadIdx.x;
    if (t >= NN * F2) return;
    int i = t / F2;
    int j2 = t - i * F2;
    int j = 2 * j2;

    float sc0 = 1.0f, sh0 = 0.0f, sc1 = 1.0f, sh1 = 0.0f;
    if (IN_BN) {
        const float inv_n = 1.0f / NN;
        float mu0 = bnacc[j] * inv_n;
        float va0 = bnacc[96 + j] * inv_n - mu0 * mu0;
        float r0  = rsqrtf(va0 + 1e-5f);
        sc0 = g[j] * r0; sh0 = be[j] - mu0 * sc0;
        float mu1 = bnacc[j + 1] * inv_n;
        float va1 = bnacc[96 + j + 1] * inv_n - mu1 * mu1;
        float r1  = rsqrtf(va1 + 1e-5f);
        sc1 = g[j + 1] * r1; sh1 = be[j + 1] - mu1 * sc1;
    }

    const uint_t* h2 = (const uint_t*)h + j2;  // column pair j within rows
    float di = dis[i];

    // self-loop
    uint_t su = h2[(size_t)i * F2];
    float vx = bflo(su), vy = bfhi(su);
    if (IN_BN) { vx = fmaxf(vx, 0.0f) * sc0 + sh0; vy = fmaxf(vy, 0.0f) * sc1 + sh1; }
    float ax = vx * di * di;
    float ay = vy * di * di;

    int k = row_ptr[i], end = row_ptr[i + 1];
    for (; k + 8 <= end; k += 8) {
        uint_t uu[8]; float ww[8];
        #pragma unroll
        for (int q = 0; q < 8; ++q) {
            int s = col[k + q];
            ww[q] = wgt[k + q];
            uu[q] = h2[(size_t)s * F2];
        }
        #pragma unroll
        for (int q = 0; q < 8; ++q) {
            float tx = bflo(uu[q]), ty = bfhi(uu[q]);
            if (IN_BN) { tx = fmaxf(tx, 0.0f) * sc0 + sh0; ty = fmaxf(ty, 0.0f) * sc1 + sh1; }
            ax = fmaf(tx, ww[q], ax); ay = fmaf(ty, ww[q], ay);
        }
    }
    for (; k < end; ++k) {
        int s = col[k];
        float w = wgt[k];
        uint_t u = h2[(size_t)s * F2];
        float tx = bflo(u), ty = bfhi(u);
        if (IN_BN) { tx = fmaxf(tx, 0.0f) * sc0 + sh0; ty = fmaxf(ty, 0.0f) * sc1 + sh1; }
        ax = fmaf(tx, w, ax); ay = fmaf(ty, w, ay);
    }
    if (OUT_BIAS) { ax += b[j]; ay += b[j + 1]; }
    ((uint_t*)A)[(size_t)i * F2 + j2] = packbf(ax, ay);
}

// ---------------- BN partial sums over relu(A), bf16 input ----------------
template<int FO>
__global__ void k_bnpart(const ushort_t* __restrict__ A, float* __restrict__ acc) {
    constexpr int F2 = FO / 2;
    __shared__ float ls[96], lq[96];
    int tid = threadIdx.x;
    if (tid < 96) { ls[tid] = 0.0f; lq[tid] = 0.0f; }
    __syncthreads();
    const uint_t* A2 = (const uint_t*)A;
    int t2 = blockIdx.x * blockDim.x + tid;
    int j2 = t2 % F2;
    int stride = gridDim.x * blockDim.x;
    float sx = 0.0f, qx = 0.0f, sy = 0.0f, qy = 0.0f;
    for (; t2 < NN * F2; t2 += stride) {
        uint_t u = A2[t2];
        float x = fmaxf(bflo(u), 0.0f), y = fmaxf(bfhi(u), 0.0f);
        sx += x; qx += x * x;
        sy += y; qy += y * y;
    }
    atomicAdd(&ls[2 * j2], sx);     atomicAdd(&ls[2 * j2 + 1], sy);
    atomicAdd(&lq[2 * j2], qx);     atomicAdd(&lq[2 * j2 + 1], qy);
    __syncthreads();
    if (tid < FO) {
        atomicAdd(&acc[tid], ls[tid]);
        atomicAdd(&acc[96 + tid], lq[tid]);
    }
}

extern "C" void kernel_launch(void* const* d_in, const int* in_sizes, int n_in,
                              void* d_out, int out_size, void* d_ws, size_t ws_size,
                              hipStream_t stream) {
    const float* x = (const float*)d_in[0];
    const int* ei = (const int*)d_in[1];
    const int* src = ei;             // edge_index[0]
    const int* dst = ei + NE;        // edge_index[1]
    const float* W1 = (const float*)d_in[2];  const float* b1 = (const float*)d_in[3];
    const float* W2 = (const float*)d_in[4];  const float* b2 = (const float*)d_in[5];
    const float* W3 = (const float*)d_in[6];  const float* b3 = (const float*)d_in[7];
    const float* W4 = (const float*)d_in[8];  const float* b4 = (const float*)d_in[9];
    const float* W5 = (const float*)d_in[10]; const float* b5 = (const float*)d_in[11];
    const float* W6 = (const float*)d_in[12]; const float* b6 = (const float*)d_in[13];
    const float* g1 = (const float*)d_in[14]; const float* be1 = (const float*)d_in[15];
    const float* g2 = (const float*)d_in[16]; const float* be2 = (const float*)d_in[17];
    const float* g3 = (const float*)d_in[18]; const float* be3 = (const float*)d_in[19];
    const float* g4 = (const float*)d_in[20]; const float* be4 = (const float*)d_in[21];

    // workspace (~21.5 MB)
    float* ws = (float*)d_ws;
    float* dis    = ws;                         // NN
    float* bnacc  = dis + NN;                   // 768
    float* wgt    = bnacc + 768;                // NE
    int* deg      = (int*)(wgt + NE);           // NN
    int* row_ptr  = deg + NN;                   // NN+1
    int* cursor   = row_ptr + NN + 1;           // NN
    int* col      = cursor + NN;                // NE
    int* bsum     = col + NE;                   // 256
    int* boff     = bsum + 256;                 // 256
    ushort_t* hB  = (ushort_t*)(boff + 256);    // NN*70 bf16
    ushort_t* aB  = hB + (size_t)NN * 70;       // NN*70 bf16
    float* out    = (float*)d_out;

    const int NB = 256;
    const dim3 DG(NDBLK, 2);
    float* bn0 = bnacc;        // L1 stats (g1,be1)
    float* bn1 = bnacc + 192;  // L2 stats (g2,be2)
    float* bn2 = bnacc + 384;  // L4 stats (g3,be3)
    float* bn3 = bnacc + 576;  // L5 stats (g4,be4)

    // ---- CSR + normalization build ----
    k_prep<<<cdiv(NN, NB), NB, 0, stream>>>(deg, bnacc);
    k_hist<<<cdiv(NE, NB), NB, 0, stream>>>(dst, deg);
    k_bsum<<<NBLK, 256, 0, stream>>>(deg, bsum);
    k_bscan<<<1, 256, 0, stream>>>(bsum, boff, row_ptr);
    k_rowptr<<<NBLK, 256, 0, stream>>>(deg, boff, row_ptr, cursor, dis);
    k_fill<<<cdiv(NE, NB), NB, 0, stream>>>(src, dst, dis, cursor, col, wgt);

    // ---- L1: dense x(88,f32)->hB(70); gather hB -> aB + b1; stats bn0 ----
    k_dense<88, 70, 0, 0, 1, 0><<<DG, 128, 0, stream>>>(x, W1, nullptr, nullptr, nullptr, nullptr, hB);
    k_gather<70, 0, 1><<<cdiv((long long)NN * 35, NB), NB, 0, stream>>>(
        hB, row_ptr, col, wgt, dis, nullptr, nullptr, nullptr, b1, aB);
    k_bnpart<70><<<35 * 56, NB, 0, stream>>>(aB, bn0);

    // ---- L2: dense bn(aB)(70)->hB(60); gather hB -> aB + b2; stats bn1 ----
    k_dense<70, 60, 1, 0, 0, 0><<<DG, 128, 0, stream>>>(aB, W2, bn0, g1, be1, nullptr, hB);
    k_gather<60, 0, 1><<<cdiv((long long)NN * 30, NB), NB, 0, stream>>>(
        hB, row_ptr, col, wgt, dis, nullptr, nullptr, nullptr, b2, aB);
    k_bnpart<60><<<30 * 56, NB, 0, stream>>>(aB, bn1);

    // ---- L3: dense bn(aB)(60)->hB(50); gather hB -> aB + b3 (A3) ----
    k_dense<60, 50, 1, 0, 0, 0><<<DG, 128, 0, stream>>>(aB, W3, bn1, g2, be2, nullptr, hB);
    k_gather<50, 0, 1><<<cdiv((long long)NN * 25, NB), NB, 0, stream>>>(
        hB, row_ptr, col, wgt, dis, nullptr, nullptr, nullptr, b3, aB);

    // ---- L4 (aggregate-first): gather aB(A3) -> hB(agg4,50); dense hB -> aB(A4,60)+b4; stats bn2 ----
    k_gather<50, 0, 0><<<cdiv((long long)NN * 25, NB), NB, 0, stream>>>(
        aB, row_ptr, col, wgt, dis, nullptr, nullptr, nullptr, nullptr, hB);
    k_dense<50, 60, 0, 1, 0, 0><<<DG, 128, 0, stream>>>(hB, W4, nullptr, nullptr, nullptr, b4, aB);
    k_bnpart<60><<<30 * 56, NB, 0, stream>>>(aB, bn2);

    // ---- L5: gather bn(aB=A4) -> hB(agg5,60); dense hB -> aB(A5,70)+b5; stats bn3 ----
    k_gather<60, 1, 0><<<cdiv((long long)NN * 30, NB), NB, 0, stream>>>(
        aB, row_ptr, col, wgt, dis, bn2, g3, be3, nullptr, hB);
    k_dense<60, 70, 0, 1, 0, 0><<<DG, 128, 0, stream>>>(hB, W5, nullptr, nullptr, nullptr, b5, aB);
    k_bnpart<70><<<35 * 56, NB, 0, stream>>>(aB, bn3);

    // ---- L6: gather bn(aB=A5) -> hB(agg6,70); dense hB -> out(88,f32)+b6 ----
    k_gather<70, 1, 0><<<cdiv((long long)NN * 35, NB), NB, 0, stream>>>(
        aB, row_ptr, col, wgt, dis, bn3, g4, be4, nullptr, hB);
    k_dense<70, 88, 0, 1, 0, 1><<<DG, 128, 0, stream>>>(hB, W6, nullptr, nullptr, nullptr, b6, out);
}